// Round 9
// baseline (7095.886 us; speedup 1.0000x reference)
//
#include <hip/hip_runtime.h>

typedef float f32x4 __attribute__((ext_vector_type(4)));
typedef int i32x4 __attribute__((ext_vector_type(4)));

#define HDIM 2048
#define BATCH 256
#define TSTEPS 300

// ws layout (bytes)
#define W8_OFF  0u          // 4 MB  : wrec^T int8-hi, MFMA B-frag order [g][ct][kb][lane][16]
#define W2_OFF  4194304u    // 1 MB  : wrec^T 2-bit lo crumbs, dword per [g][ct][kb][lane]
#define RHI_OFF 5242880u    // 1 MB  : r hi int8, 2x[256][2048]
#define RLO_OFF 6291456u    // 1 MB  : r lo int8, 2x[256][2048]
#define HWS_OFF 7340032u    // 2 MB  : h f32 [256][2048]
#define WI_OFF  9437184u    // 32 KB : wi_full f32 [4][2048]
#define WO_OFF  9469952u    // 16 KB : wo_full f32 [2][2048]
#define SC_OFF  9486336u    // 8 KB  : per-col scale s[2048]

__device__ inline float tanh_fast(float x) {
  float e = __expf(2.0f * x);
  return 1.0f - 2.0f / (e + 1.0f);
}

// s[j] = max_k |wrec[j][k]| / 127,  wrec[j][k] = rec_noise[j][k] + m[j,:].n[k,:]
__global__ void prep_scale(const float* __restrict__ rec_noise,
                           const float* __restrict__ m, const float* __restrict__ n,
                           float* __restrict__ s) {
  int w = threadIdx.x >> 6, l = threadIdx.x & 63;
  int j = blockIdx.x * 4 + w;
  float m0 = m[j * 2], m1 = m[j * 2 + 1];
  float vmax = 0.f;
  for (int it = 0; it < HDIM / 64; ++it) {
    int k = it * 64 + l;
    float v = rec_noise[(size_t)j * HDIM + k] + m0 * n[k * 2] + m1 * n[k * 2 + 1];
    vmax = fmaxf(vmax, fabsf(v));
  }
#pragma unroll
  for (int d = 1; d < 64; d <<= 1) vmax = fmaxf(vmax, __shfl_xor(vmax, d, 64));
  if (l == 0) s[j] = fmaxf(vmax, 1e-20f) / 127.f;
}

// int8-hi bytes (B-frag order, verified round-7/8) + 2-bit lo crumbs (verified round-8).
__global__ void prep_w8w2(const float* __restrict__ rec_noise,
                          const float* __restrict__ m, const float* __restrict__ n,
                          const float* __restrict__ s,
                          char* __restrict__ W8, unsigned* __restrict__ W2) {
  int gid = blockIdx.x * 256 + threadIdx.x;   // [0, 262144)
  int lane = gid & 63;
  int kb = (gid >> 6) & 31;
  int ct = (gid >> 11) & 3;
  int g = gid >> 13;                           // 64-col group [0,32)
  int col = g * 64 + ct * 16 + (lane & 15);
  int kbase = kb * 64 + (lane >> 4) * 16;
  float sc = s[col];
  float m0 = m[col * 2], m1 = m[col * 2 + 1];
  unsigned crumbs = 0u;
  size_t b8 = (size_t)((lane << 4) | (kb << 10) | (ct << 15)) + ((size_t)g << 17);
#pragma unroll 4
  for (int i = 0; i < 16; ++i) {
    int k = kbase + i;
    float v = (rec_noise[(size_t)col * HDIM + k] + m0 * n[k * 2] + m1 * n[k * 2 + 1]) / sc;
    int q8 = __float2int_rn(v);
    q8 = max(-127, min(127, q8));
    float f = v - (float)q8;
    int q2 = (int)floorf(4.f * f);
    q2 = max(-2, min(1, q2));
    W8[b8 + i] = (char)q8;
    crumbs |= (unsigned)(q2 + 2) << (2 * i);
  }
  W2[gid] = crumbs;
}

// wi_full, wo_full, r0 (hi/lo int8), h init
__global__ void prep_small(const float* __restrict__ wi, const float* __restrict__ si,
                           const float* __restrict__ wo, const float* __restrict__ so,
                           const float* __restrict__ h0,
                           float* __restrict__ wi_full, float* __restrict__ wo_full,
                           char* __restrict__ rhi0, char* __restrict__ rlo0,
                           float* __restrict__ hws) {
  int idx = blockIdx.x * 256 + threadIdx.x;
  if (idx < BATCH * HDIM) {
    int j = idx & (HDIM - 1);
    float hv = h0[j];
    hws[idx] = hv;
    int Q = __float2int_rn(16256.f * tanh_fast(hv));
    int ah = (Q + 64) >> 7;
    int al = Q - (ah << 7);
    rhi0[idx] = (char)ah;
    rlo0[idx] = (char)al;
  }
  if (idx < 4 * HDIM) wi_full[idx] = wi[idx] * si[idx >> 11];
  if (idx < 2 * HDIM) {
    int o = idx >> 11, j = idx & (HDIM - 1);
    wo_full[idx] = wo[j * 2 + o] * so[o];
  }
}

// One RNN timestep. Grid 256 blocks x 512 threads.
// bid -> xv=bid&7 (XCD-friendly 256-col band), rg=(bid>>3)&7 (32 rows), cs=bid>>6 (64-col sub).
// Wave w: wrow=w>>2 (16-row tile), wcol=w&3 (16-col tile).
// rec = s*(128*(ahi.q8) + (alo.q8) + 16*(ahi.wlo'))/16256  (round-8 floor-proven numerics)
__global__ __launch_bounds__(512) void step_k(
    const float* __restrict__ inp, const float* __restrict__ noise,
    const char* __restrict__ W8, const unsigned* __restrict__ W2,
    const char* __restrict__ rrh, const char* __restrict__ rrl,
    char* __restrict__ rwh, char* __restrict__ rwl,
    float* __restrict__ hws, const float* __restrict__ wi_full,
    const float* __restrict__ wo_full, const float* __restrict__ scales,
    float* __restrict__ out, int t) {
  __shared__ float red[8][16][2];

  const int tid = threadIdx.x;
  const int l = tid & 63, w = tid >> 6;
  const int lr = l & 15, hi = l >> 4;
  const int wrow = w >> 2, wcol = w & 3;
  const int bid = blockIdx.x;
  const int xv = bid & 7, rg = (bid >> 3) & 7, cs = bid >> 6;
  const int colg = xv * 4 + cs;                 // 64-col group [0,32)
  const int colbase = colg * 64 + wcol * 16;
  const int col = colbase + lr;
  const int rowbase = rg * 32 + wrow * 16;

  // ---- early loads: noise + input for this step (overlap with GEMM) ----
  float nz[4], xd[4];
  float wic0 = wi_full[col], wic1 = wi_full[HDIM + col];
  float wic2 = wi_full[2 * HDIM + col], wic3 = wi_full[3 * HDIM + col];
#pragma unroll
  for (int q = 0; q < 4; ++q) {
    const int brow = rowbase + hi * 4 + q;
    nz[q] = noise[((size_t)brow * TSTEPS + t) * HDIM + col];
    float4 x = *(const float4*)(inp + ((size_t)brow * TSTEPS + t) * 4);
    xd[q] = x.x * wic0 + x.y * wic1 + x.z * wic2 + x.w * wic3;
  }

  // ---- GEMM: 32 rows handled as one 16-row tile per wave, 3 int8 passes ----
  const i32x4* ahp = (const i32x4*)(rrh + (size_t)(rowbase + lr) * HDIM + hi * 16);
  const i32x4* alp = (const i32x4*)(rrl + (size_t)(rowbase + lr) * HDIM + hi * 16);
  const i32x4* bwp = (const i32x4*)(W8 + (size_t)colg * 131072 + wcol * 32768 + l * 16);
  const unsigned* w2p = W2 + ((size_t)colg * 4 + wcol) * 2048 + l;

  i32x4 ahr[8], alr[8], bwr[8];
  unsigned w2r[8];
#pragma unroll
  for (int i = 0; i < 8; ++i) {
    ahr[i] = ahp[i * 4];
    alr[i] = alp[i * 4];
    bwr[i] = bwp[i * 64];
    w2r[i] = w2p[i * 64];
  }
  i32x4 accA = {0, 0, 0, 0}, accB = {0, 0, 0, 0}, accC = {0, 0, 0, 0};
#pragma unroll
  for (int kb = 0; kb < 32; ++kb) {
    i32x4 bW = bwr[kb & 7];
    unsigned v = w2r[kb & 7];
    i32x4 bL;
#pragma unroll
    for (int g = 0; g < 4; ++g) {
      unsigned vg = (v >> (8 * g)) & 0xFFu;
      unsigned tt = (vg | (vg << 12)) & 0x000F000Fu;
      tt = (tt | (tt << 6)) & 0x03030303u;
      bL[g] = (int)__builtin_amdgcn_perm(0u, 0x0301FFFDu, tt);
    }
    i32x4 aH = ahr[kb & 7], aL = alr[kb & 7];
    accA = __builtin_amdgcn_mfma_i32_16x16x64_i8(aH, bW, accA, 0, 0, 0);
    accB = __builtin_amdgcn_mfma_i32_16x16x64_i8(aL, bW, accB, 0, 0, 0);
    accC = __builtin_amdgcn_mfma_i32_16x16x64_i8(aH, bL, accC, 0, 0, 0);
    if (kb < 24) {
      ahr[kb & 7] = ahp[(kb + 8) * 4];
      alr[kb & 7] = alp[(kb + 8) * 4];
      bwr[kb & 7] = bwp[(kb + 8) * 64];
      w2r[kb & 7] = w2p[(kb + 8) * 64];
    }
  }

  // ---- h update + write r_{t+1} ----
  const float swq = scales[col] * (1.f / 16256.f);
  float ro[4];
#pragma unroll
  for (int q = 0; q < 4; ++q) {
    const int brow = rowbase + hi * 4 + q;
    float rec = swq * (128.f * (float)accA[q] + (float)accB[q] + 16.f * (float)accC[q]);
    float hv = hws[(size_t)brow * HDIM + col];
    float hn = 0.8f * hv + 0.05f * nz[q] + 0.2f * (rec + xd[q]);
    hws[(size_t)brow * HDIM + col] = hn;
    float r_ = tanh_fast(hn);
    ro[q] = r_;
    int Q = __float2int_rn(16256.f * r_);
    int ah = (Q + 64) >> 7;
    int al = Q - (ah << 7);
    rwh[(size_t)brow * HDIM + col] = (char)ah;
    rwl[(size_t)brow * HDIM + col] = (char)al;
  }

  // ---- out_t: wave lr-reduce -> LDS cross-wave(4 col-tiles) reduce -> atomicAdd ----
  const float wo0 = wo_full[col], wo1 = wo_full[HDIM + col];
#pragma unroll
  for (int q = 0; q < 4; ++q) {
    float p0 = ro[q] * wo0, p1 = ro[q] * wo1;
    p0 += __shfl_xor(p0, 1, 64); p1 += __shfl_xor(p1, 1, 64);
    p0 += __shfl_xor(p0, 2, 64); p1 += __shfl_xor(p1, 2, 64);
    p0 += __shfl_xor(p0, 4, 64); p1 += __shfl_xor(p1, 4, 64);
    p0 += __shfl_xor(p0, 8, 64); p1 += __shfl_xor(p1, 8, 64);
    if (lr == 0) {
      if (wcol == 0) { red[w][hi * 4 + q][0] = p0; red[w][hi * 4 + q][1] = p1; }
    }
    __syncthreads();
    if (lr == 0 && wcol != 0) {
      atomicAdd(&red[wrow * 4][hi * 4 + q][0], p0);
      atomicAdd(&red[wrow * 4][hi * 4 + q][1], p1);
    }
    __syncthreads();
    if (lr == 0 && wcol == 0) {
      const int brow = rowbase + hi * 4 + q;
      float* op = out + (size_t)brow * (TSTEPS * 2) + (size_t)t * 2;
      atomicAdd(op, red[w][hi * 4 + q][0]);
      atomicAdd(op + 1, red[w][hi * 4 + q][1]);
    }
  }
}

extern "C" void kernel_launch(void* const* d_in, const int* in_sizes, int n_in,
                              void* d_out, int out_size, void* d_ws, size_t ws_size,
                              hipStream_t stream) {
  const float* inp = (const float*)d_in[0];
  const float* noise = (const float*)d_in[1];
  const float* wi = (const float*)d_in[2];
  const float* si = (const float*)d_in[3];
  const float* m = (const float*)d_in[4];
  const float* n = (const float*)d_in[5];
  const float* rec_noise = (const float*)d_in[6];
  const float* wo = (const float*)d_in[7];
  const float* so = (const float*)d_in[8];
  const float* h0 = (const float*)d_in[9];

  char* ws = (char*)d_ws;
  char* W8 = ws + W8_OFF;
  unsigned* W2 = (unsigned*)(ws + W2_OFF);
  char* rhi = ws + RHI_OFF;
  char* rlo = ws + RLO_OFF;
  float* hws = (float*)(ws + HWS_OFF);
  float* wi_full = (float*)(ws + WI_OFF);
  float* wo_full = (float*)(ws + WO_OFF);
  float* sc = (float*)(ws + SC_OFF);
  float* outp = (float*)d_out;

  // rebuild proxy params every call (ws poisoned before timing)
  prep_scale<<<512, 256, 0, stream>>>(rec_noise, m, n, sc);
  prep_w8w2<<<1024, 256, 0, stream>>>(rec_noise, m, n, sc, W8, W2);
  prep_small<<<2048, 256, 0, stream>>>(wi, si, wo, so, h0, wi_full, wo_full,
                                       rhi, rlo, hws);
  hipMemsetAsync(d_out, 0, (size_t)out_size * sizeof(float), stream);

  // 300 dependent step dispatches; kernel boundary = global barrier + coherence
  for (int t = 0; t < TSTEPS; ++t) {
    const char* rrh = rhi + (size_t)(t & 1) * (BATCH * HDIM);
    const char* rrl = rlo + (size_t)(t & 1) * (BATCH * HDIM);
    char* rwh = rhi + (size_t)((t + 1) & 1) * (BATCH * HDIM);
    char* rwl = rlo + (size_t)((t + 1) & 1) * (BATCH * HDIM);
    step_k<<<256, 512, 0, stream>>>(inp, noise, W8, W2, rrh, rrl, rwh, rwl,
                                    hws, wi_full, wo_full, sc, outp, t);
  }
}

// Round 11
// 6658.114 us; speedup vs baseline: 1.0658x; 1.0658x over previous
//
#include <hip/hip_runtime.h>

typedef float f32x4 __attribute__((ext_vector_type(4)));
typedef int i32x4 __attribute__((ext_vector_type(4)));

#define HDIM 2048
#define BATCH 256
#define TSTEPS 300
#define NBLK 256
#define NTHR 512

// ws layout (bytes)
#define W8_OFF  0u          // 4 MB  : wrec^T int8-hi, MFMA B-frag order [g][ct][kb][lane][16]
#define W2_OFF  4194304u    // 1 MB  : wrec^T 2-bit lo crumbs
#define RHI_OFF 5242880u    // 1 MB  : r hi int8, 2x[256][2048]
#define RLO_OFF 6291456u    // 1 MB  : r lo int8, 2x[256][2048]
#define WI_OFF  7340032u    // 32 KB : wi_full f32 [4][2048]
#define WO_OFF  7372800u    // 16 KB : wo_full f32 [2][2048]
#define SC_OFF  7389184u    // 8 KB  : per-col scale s[2048]
#define BAR_OFF 7397376u    // 4 KB  : flags

#define AGENT __HIP_MEMORY_SCOPE_AGENT

__device__ inline float tanh_fast(float x) {
  float e = __expf(2.0f * x);
  return 1.0f - 2.0f / (e + 1.0f);
}

// MALL-direct (bypass L1+L2) 16B load; completion tracked by vmcnt (in-order).
__device__ inline i32x4 ld16cc(const char* p) {
  i32x4 r;
  asm volatile("global_load_dwordx4 %0, %1, off sc0 sc1"
               : "=&v"(r) : "v"(p) : "memory");
  return r;
}

// s[j] = max_k |wrec[j][k]| / 127 (verified R8)
__global__ void prep_scale(const float* __restrict__ rec_noise,
                           const float* __restrict__ m, const float* __restrict__ n,
                           float* __restrict__ s) {
  int w = threadIdx.x >> 6, l = threadIdx.x & 63;
  int j = blockIdx.x * 4 + w;
  float m0 = m[j * 2], m1 = m[j * 2 + 1];
  float vmax = 0.f;
  for (int it = 0; it < HDIM / 64; ++it) {
    int k = it * 64 + l;
    float v = rec_noise[(size_t)j * HDIM + k] + m0 * n[k * 2] + m1 * n[k * 2 + 1];
    vmax = fmaxf(vmax, fabsf(v));
  }
#pragma unroll
  for (int d = 1; d < 64; d <<= 1) vmax = fmaxf(vmax, __shfl_xor(vmax, d, 64));
  if (l == 0) s[j] = fmaxf(vmax, 1e-20f) / 127.f;
}

// int8-hi (B-frag order) + 2-bit lo crumbs (verified R8)
__global__ void prep_w8w2(const float* __restrict__ rec_noise,
                          const float* __restrict__ m, const float* __restrict__ n,
                          const float* __restrict__ s,
                          char* __restrict__ W8, unsigned* __restrict__ W2) {
  int gid = blockIdx.x * 256 + threadIdx.x;   // [0, 262144)
  int lane = gid & 63;
  int kb = (gid >> 6) & 31;
  int ct = (gid >> 11) & 3;
  int g = gid >> 13;                           // [0,32)
  int col = g * 64 + ct * 16 + (lane & 15);
  int kbase = kb * 64 + (lane >> 4) * 16;
  float sc = s[col];
  float m0 = m[col * 2], m1 = m[col * 2 + 1];
  unsigned crumbs = 0u;
  size_t b8 = (size_t)((lane << 4) | (kb << 10) | (ct << 15)) + ((size_t)g << 17);
#pragma unroll 4
  for (int i = 0; i < 16; ++i) {
    int k = kbase + i;
    float v = (rec_noise[(size_t)col * HDIM + k] + m0 * n[k * 2] + m1 * n[k * 2 + 1]) / sc;
    int q8 = __float2int_rn(v);
    q8 = max(-127, min(127, q8));
    float f = v - (float)q8;
    int q2 = (int)floorf(4.f * f);
    q2 = max(-2, min(1, q2));
    W8[b8 + i] = (char)q8;
    crumbs |= (unsigned)(q2 + 2) << (2 * i);
  }
  W2[gid] = crumbs;
}

// wi_full, wo_full, r0 hi/lo (verified R8)
__global__ void prep_small(const float* __restrict__ wi, const float* __restrict__ si,
                           const float* __restrict__ wo, const float* __restrict__ so,
                           const float* __restrict__ h0,
                           float* __restrict__ wi_full, float* __restrict__ wo_full,
                           char* __restrict__ rhi0, char* __restrict__ rlo0) {
  int idx = blockIdx.x * 256 + threadIdx.x;
  if (idx < BATCH * HDIM) {
    int j = idx & (HDIM - 1);
    int Q = __float2int_rn(16256.f * tanh_fast(h0[j]));
    int ah = (Q + 64) >> 7;
    int al = Q - (ah << 7);
    rhi0[idx] = (char)ah;
    rlo0[idx] = (char)al;
  }
  if (idx < 4 * HDIM) wi_full[idx] = wi[idx] * si[idx >> 11];
  if (idx < 2 * HDIM) {
    int o = idx >> 11, j = idx & (HDIM - 1);
    wo_full[idx] = wo[j * 2 + o] * so[o];
  }
}

// Persistent RNN: pure bid partition (rg=bid>>5 rows, cg=bid&31 cols). Per-step
// sync = per-row-group flag barrier (32 blocks). r stores are 1-byte sc0sc1
// write-through (no dirty L2 => no wbl2); A loads are sc0sc1 MALL-direct (no inv).
// Zero cache-maintenance ops per step.
__global__ __launch_bounds__(NTHR, 1) void rnn_run(
    const float* __restrict__ inp, const float* __restrict__ noise,
    const char* __restrict__ W8, const unsigned* __restrict__ W2,
    char* __restrict__ rhi, char* __restrict__ rlo,
    const float* __restrict__ wi_full, const float* __restrict__ wo_full,
    const float* __restrict__ scales, const float* __restrict__ h0,
    float* __restrict__ out, unsigned* __restrict__ bar) {
  extern __shared__ char Wlds[];  // 128 KB: W-hi slice (frag order)

  const int tid = threadIdx.x;
  const int l = tid & 63, w = tid >> 6;
  const int lr = l & 15, hi = l >> 4;
  const int wrow = w >> 2, wcol = w & 3;
  const int bid = blockIdx.x;
  const int rg = bid >> 5, cg = bid & 31;       // 32 rows x 64 cols per block
  const int rowb = rg * 32 + wrow * 16;         // this wave's 16 rows
  const int colw = cg * 64 + wcol * 16 + lr;    // this lane's output column

  // one-time: W-hi slice -> LDS (plain cached loads; read-only)
  {
    const f32x4* src = (const f32x4*)(W8 + (size_t)cg * 131072);
    f32x4* dst = (f32x4*)Wlds;
    for (int u = tid; u < 8192; u += NTHR) dst[u] = src[u];
  }
  // one-time: W-lo crumbs for this wave's 16 cols -> 32 VGPRs (R8-proven mapping)
  unsigned w2r[32];
  {
    const unsigned* w2g = W2 + ((size_t)cg * 4 + wcol) * 2048 + l;
#pragma unroll
    for (int kb = 0; kb < 32; ++kb) w2r[kb] = w2g[kb * 64];
  }

  const float swq = scales[colw] * (1.f / 16256.f);
  const float wic0 = wi_full[colw], wic1 = wi_full[HDIM + colw];
  const float wic2 = wi_full[2 * HDIM + colw], wic3 = wi_full[3 * HDIM + colw];
  const float wo0 = wo_full[colw], wo1 = wo_full[HDIM + colw];

  float h[4];
  {
    float a = h0[colw];
#pragma unroll
    for (int q = 0; q < 4; ++q) h[q] = a;
  }
  __syncthreads();

  // prefetch t=0 noise + input-dot (plain cached loads)
  float nz[4], xd[4];
#pragma unroll
  for (int q = 0; q < 4; ++q) {
    const int brow = rowb + hi * 4 + q;
    nz[q] = noise[((size_t)brow * TSTEPS + 0) * HDIM + colw];
    float4 x = *(const float4*)(inp + ((size_t)brow * TSTEPS + 0) * 4);
    xd[q] = x.x * wic0 + x.y * wic1 + x.z * wic2 + x.w * wic3;
  }

  const char* ldsB = Wlds + wcol * 32768 + l * 16;   // + kb*1024
  unsigned* myflag = bar + rg * 32 + cg;
  const unsigned* pollp = bar + rg * 32 + (l & 31);

// one K-step: wait ring pair KB, unpack lo, 3 MFMAs, refill pair KB+12
#define STEPK(KB, VC)                                                          \
  {                                                                            \
    asm volatile("s_waitcnt vmcnt(" #VC ")" ::: "memory");                     \
    __builtin_amdgcn_sched_barrier(0);                                         \
    i32x4 bW = *(const i32x4*)(ldsB + (KB) * 1024);                            \
    unsigned v_ = w2r[(KB)];                                                   \
    i32x4 bL;                                                                  \
    {                                                                          \
      unsigned vg, tt;                                                         \
      vg = v_ & 0xFFu; tt = (vg | (vg << 12)) & 0x000F000Fu;                   \
      tt = (tt | (tt << 6)) & 0x03030303u;                                     \
      bL[0] = (int)__builtin_amdgcn_perm(0u, 0x0301FFFDu, tt);                 \
      vg = (v_ >> 8) & 0xFFu; tt = (vg | (vg << 12)) & 0x000F000Fu;            \
      tt = (tt | (tt << 6)) & 0x03030303u;                                     \
      bL[1] = (int)__builtin_amdgcn_perm(0u, 0x0301FFFDu, tt);                 \
      vg = (v_ >> 16) & 0xFFu; tt = (vg | (vg << 12)) & 0x000F000Fu;           \
      tt = (tt | (tt << 6)) & 0x03030303u;                                     \
      bL[2] = (int)__builtin_amdgcn_perm(0u, 0x0301FFFDu, tt);                 \
      vg = (v_ >> 24) & 0xFFu; tt = (vg | (vg << 12)) & 0x000F000Fu;           \
      tt = (tt | (tt << 6)) & 0x03030303u;                                     \
      bL[3] = (int)__builtin_amdgcn_perm(0u, 0x0301FFFDu, tt);                 \
    }                                                                          \
    accA = __builtin_amdgcn_mfma_i32_16x16x64_i8(A[(KB) % 12], bW, accA, 0, 0, 0); \
    accB = __builtin_amdgcn_mfma_i32_16x16x64_i8(L[(KB) % 12], bW, accB, 0, 0, 0); \
    accC = __builtin_amdgcn_mfma_i32_16x16x64_i8(A[(KB) % 12], bL, accC, 0, 0, 0); \
    if ((KB) < 20) {                                                           \
      A[(KB) % 12] = ld16cc(ahp + ((KB) + 12) * 64);                           \
      L[(KB) % 12] = ld16cc(alp + ((KB) + 12) * 64);                           \
    }                                                                          \
  }

  for (int t = 0; t < TSTEPS; ++t) {
    // ---- gate: wait my row-group's 32 producers to have published step t ----
    if (t > 0) {
      const unsigned tgt = (unsigned)t;
      for (;;) {
        unsigned fv = __hip_atomic_load(pollp, __ATOMIC_RELAXED, AGENT);
        if (__all((int)(fv >= tgt))) break;
      }
      __builtin_amdgcn_sched_barrier(0);
    }

    const char* rrh = rhi + (size_t)(t & 1) * (BATCH * HDIM);
    const char* rrl = rlo + (size_t)(t & 1) * (BATCH * HDIM);
    char* rwh = rhi + (size_t)((t + 1) & 1) * (BATCH * HDIM);
    char* rwl = rlo + (size_t)((t + 1) & 1) * (BATCH * HDIM);
    const char* ahp = rrh + (size_t)(rowb + lr) * HDIM + hi * 16;
    const char* alp = rrl + (size_t)(rowb + lr) * HDIM + hi * 16;

    // ---- GEMM: 12-pair ring, hand-counted vmcnt; W from LDS, lo from VGPR ----
    i32x4 A[12], L[12];
#pragma unroll
    for (int s = 0; s < 12; ++s) {
      A[s] = ld16cc(ahp + s * 64);
      L[s] = ld16cc(alp + s * 64);
    }
    i32x4 accA = {0, 0, 0, 0}, accB = {0, 0, 0, 0}, accC = {0, 0, 0, 0};
    STEPK(0, 22)  STEPK(1, 22)  STEPK(2, 22)  STEPK(3, 22)  STEPK(4, 22)
    STEPK(5, 22)  STEPK(6, 22)  STEPK(7, 22)  STEPK(8, 22)  STEPK(9, 22)
    STEPK(10, 22) STEPK(11, 22) STEPK(12, 22) STEPK(13, 22) STEPK(14, 22)
    STEPK(15, 22) STEPK(16, 22) STEPK(17, 22) STEPK(18, 22) STEPK(19, 22)
    STEPK(20, 22) STEPK(21, 20) STEPK(22, 18) STEPK(23, 16) STEPK(24, 14)
    STEPK(25, 12) STEPK(26, 10) STEPK(27, 8)  STEPK(28, 6)  STEPK(29, 4)
    STEPK(30, 2)  STEPK(31, 0)

    // ---- h update + write r_{t+1} as 1-byte sc0sc1 write-through stores ----
    float ro[4];
#pragma unroll
    for (int q = 0; q < 4; ++q) {
      float rec = swq * (128.f * (float)accA[q] + (float)accB[q] + 16.f * (float)accC[q]);
      float hn = 0.8f * h[q] + 0.05f * nz[q] + 0.2f * (rec + xd[q]);
      h[q] = hn;
      float r_ = tanh_fast(hn);
      ro[q] = r_;
      int Q = __float2int_rn(16256.f * r_);
      int ah = (Q + 64) >> 7;
      int al = Q - (ah << 7);
      const size_t off = (size_t)(rowb + hi * 4 + q) * HDIM + colw;
      __hip_atomic_store((unsigned char*)(rwh + off), (unsigned char)(char)ah,
                         __ATOMIC_RELAXED, AGENT);
      __hip_atomic_store((unsigned char*)(rwl + off), (unsigned char)(char)al,
                         __ATOMIC_RELAXED, AGENT);
    }

    // ---- publish: syncthreads drains all waves' stores (vmcnt0 -> at MALL) ----
    __syncthreads();
    if (t + 1 < TSTEPS && tid == 0)
      __hip_atomic_store(myflag, (unsigned)(t + 1), __ATOMIC_RELAXED, AGENT);

    // ---- hidden before next gate: out_t + t+1 prefetch (pinned) ----
#pragma unroll
    for (int q = 0; q < 4; ++q) {
      float p0 = ro[q] * wo0, p1 = ro[q] * wo1;
      p0 += __shfl_xor(p0, 1, 64); p1 += __shfl_xor(p1, 1, 64);
      p0 += __shfl_xor(p0, 2, 64); p1 += __shfl_xor(p1, 2, 64);
      p0 += __shfl_xor(p0, 4, 64); p1 += __shfl_xor(p1, 4, 64);
      p0 += __shfl_xor(p0, 8, 64); p1 += __shfl_xor(p1, 8, 64);
      if (lr == 0) {
        const int brow = rowb + hi * 4 + q;
        float* op = out + (size_t)brow * (TSTEPS * 2) + (size_t)t * 2;
        atomicAdd(op, p0);
        atomicAdd(op + 1, p1);
      }
    }
    if (t + 1 < TSTEPS) {
#pragma unroll
      for (int q = 0; q < 4; ++q) {
        const int brow = rowb + hi * 4 + q;
        nz[q] = noise[((size_t)brow * TSTEPS + (t + 1)) * HDIM + colw];
        float4 x = *(const float4*)(inp + ((size_t)brow * TSTEPS + (t + 1)) * 4);
        xd[q] = x.x * wic0 + x.y * wic1 + x.z * wic2 + x.w * wic3;
      }
      // pin: force the prefetch loads to issue before the gate poll
#pragma unroll
      for (int q = 0; q < 4; ++q)
        asm volatile("" :: "v"(nz[q]), "v"(xd[q]));
    }
  }
#undef STEPK
}

extern "C" void kernel_launch(void* const* d_in, const int* in_sizes, int n_in,
                              void* d_out, int out_size, void* d_ws, size_t ws_size,
                              hipStream_t stream) {
  const float* inp = (const float*)d_in[0];
  const float* noise = (const float*)d_in[1];
  const float* wi = (const float*)d_in[2];
  const float* si = (const float*)d_in[3];
  const float* m = (const float*)d_in[4];
  const float* n = (const float*)d_in[5];
  const float* rec_noise = (const float*)d_in[6];
  const float* wo = (const float*)d_in[7];
  const float* so = (const float*)d_in[8];
  const float* h0 = (const float*)d_in[9];

  char* ws = (char*)d_ws;
  char* W8 = ws + W8_OFF;
  unsigned* W2 = (unsigned*)(ws + W2_OFF);
  char* rhi = ws + RHI_OFF;
  char* rlo = ws + RLO_OFF;
  float* wi_full = (float*)(ws + WI_OFF);
  float* wo_full = (float*)(ws + WO_OFF);
  float* sc = (float*)(ws + SC_OFF);
  unsigned* bar = (unsigned*)(ws + BAR_OFF);
  float* outp = (float*)d_out;

  // rebuild proxy params every call (ws poisoned before timing)
  prep_scale<<<512, 256, 0, stream>>>(rec_noise, m, n, sc);
  prep_w8w2<<<1024, 256, 0, stream>>>(rec_noise, m, n, sc, W8, W2);
  prep_small<<<2048, 256, 0, stream>>>(wi, si, wo, so, h0, wi_full, wo_full, rhi, rlo);
  hipMemsetAsync(d_out, 0, (size_t)out_size * sizeof(float), stream);
  hipMemsetAsync(bar, 0, 4096, stream);

  hipFuncSetAttribute((const void*)rnn_run, hipFuncAttributeMaxDynamicSharedMemorySize, 131072);
  const char* W8c = W8;
  const unsigned* W2c = W2;
  const float* scc = sc;
  const float* wic = wi_full;
  const float* woc = wo_full;
  void* kargs[12] = {(void*)&inp, (void*)&noise, (void*)&W8c, (void*)&W2c,
                     (void*)&rhi, (void*)&rlo, (void*)&wic, (void*)&woc,
                     (void*)&scc, (void*)&h0, (void*)&outp, (void*)&bar};
  hipError_t lerr = hipLaunchCooperativeKernel((void*)rnn_run, dim3(NBLK), dim3(NTHR),
                                               kargs, 131072, stream);
  if (lerr != hipSuccess) {
    // 256 blocks x 128KB LDS => 1 block/CU on 256 CUs: co-resident in practice
    rnn_run<<<dim3(NBLK), dim3(NTHR), 131072, stream>>>(
        inp, noise, W8, W2, rhi, rlo, wi_full, wo_full, sc, h0, outp, bar);
  }
}

// Round 12
// 4384.553 us; speedup vs baseline: 1.6184x; 1.5185x over previous
//
#include <hip/hip_runtime.h>

typedef float f32x4 __attribute__((ext_vector_type(4)));
typedef __bf16 bf16x8 __attribute__((ext_vector_type(8)));

#define HDIM 2048
#define BATCH 256
#define TSTEPS 300
#define NBLK 256
#define NTHR 256

// ws layout (bytes)
#define WT_OFF 0u            // 2048*2048 bf16 = 8388608 B, MFMA B-frag order
#define RBUF_OFF 8388608u    // 2 * 256*2048 bf16 = 2097152 B (double buffer)
#define WI_OFF 10485760u     // 4*2048 f32 = 32768 B
#define WO_OFF 10518528u     // 2*2048 f32 = 16384 B  ([o][j] layout)
#define BAR_OFF 10534912u    // 4 KB barrier area

// bar u32 indices
#define B_FLAGS 0                     // flags[256], contiguous
#define B_RDY(x) (256 + (x) * 32)     // per-XCD ready generation (128B apart)
#define B_GCNT0 520                   // init barrier counter
#define B_XTOT(x) (544 + (x))         // per-XCD registration counters

#define AGENT __HIP_MEMORY_SCOPE_AGENT

__device__ inline float tanh_fast(float x) {
  float e = __expf(2.0f * x);
  return 1.0f - 2.0f / (e + 1.0f);
}

__device__ inline unsigned short f2bf(float f) {
  union { float f; unsigned u; } v; v.f = f;
  unsigned r = v.u + 0x7fffu + ((v.u >> 16) & 1u);
  return (unsigned short)(r >> 16);
}

// write-through (sc0 sc1) 16-bit store: lands at coherence point, no dirty L2 line.
// R11-proven: vmcnt-drain + relaxed MALL flag afterwards is a correct release.
__device__ inline void st_bf16_wt(unsigned short* p, unsigned short v) {
  unsigned vv = v;
  asm volatile("global_store_short %0, %1, off sc0 sc1" :: "v"(p), "v"(vv) : "memory");
}

// Build wrec^T in bf16, MFMA B-frag order (verified rounds 1-4)
__global__ void prep_wt(const float* __restrict__ rec_noise,
                        const float* __restrict__ m, const float* __restrict__ n,
                        unsigned short* __restrict__ WT) {
  int base = (blockIdx.x * 256 + threadIdx.x) * 4;
#pragma unroll
  for (int ii = 0; ii < 4; ++ii) {
    int e = base + ii;
    int i = e & 7;
    int lane = (e >> 3) & 63;
    int t16 = (e >> 9) & 1;
    int kb = (e >> 10) & 63;
    int jg = e >> 16;
    int j = jg * 32 + t16 * 16 + (lane & 15);
    int k = kb * 32 + (lane >> 4) * 8 + i;
    float v = rec_noise[(size_t)j * HDIM + k] + m[j * 2] * n[k * 2] + m[j * 2 + 1] * n[k * 2 + 1];
    WT[e] = f2bf(v);
  }
}

__global__ void prep_small(const float* __restrict__ wi, const float* __restrict__ si,
                           const float* __restrict__ wo, const float* __restrict__ so,
                           const float* __restrict__ h0,
                           float* __restrict__ wi_full, float* __restrict__ wo_full,
                           unsigned short* __restrict__ r0) {
  int idx = blockIdx.x * 256 + threadIdx.x;
  if (idx < BATCH * HDIM) {
    int j = idx & (HDIM - 1);
    r0[idx] = f2bf(tanh_fast(h0[j]));
  }
  if (idx < 4 * HDIM) wi_full[idx] = wi[idx] * si[idx >> 11];
  if (idx < 2 * HDIM) {
    int o = idx >> 11, j = idx & (HDIM - 1);
    wo_full[idx] = wo[j * 2 + o] * so[o];
  }
}

// R4 structure; barrier chain thinned: write-through stores (no wbl2), flag-array
// arrive (no RMW chain), leader polls flags directly (no gen relay), leader
// ACQUIRE fence (L2 inv) + ready flag, siblings L1-inv. Cached A-loads.
__global__ __launch_bounds__(NTHR, 1) void rnn_run(
    const float* __restrict__ inp, const float* __restrict__ noise,
    const unsigned short* __restrict__ WT, unsigned short* __restrict__ rbuf,
    const float* __restrict__ wi_full, const float* __restrict__ wo_full,
    const float* __restrict__ h0, float* __restrict__ out,
    unsigned* __restrict__ bar) {
  extern __shared__ unsigned short Wlds[];  // 128 KB: this block's W slice

  const int tid = threadIdx.x;
  const int l = tid & 63, w = tid >> 6;
  const int bid = blockIdx.x;
  const int mg = bid >> 6, jg = bid & 63;
  const int lr = l & 15, hi = l >> 4;
  const int b0w = mg * 64 + w * 16;
  const int col0 = jg * 32 + lr;

  // ---- registration: discover XCD, elect per-XCD leader (R4-proven) ----
  if (tid == 0) {
    unsigned xcc_ = (unsigned)__builtin_amdgcn_s_getreg((31u << 11) | 20u) & 7u;  // HW_REG_XCC_ID
    unsigned idx_ = __hip_atomic_fetch_add(bar + B_XTOT(xcc_), 1u, __ATOMIC_RELAXED, AGENT);
    __hip_atomic_fetch_add(bar + B_GCNT0, 1u, __ATOMIC_RELEASE, AGENT);
    while (__hip_atomic_load(bar + B_GCNT0, __ATOMIC_RELAXED, AGENT) < (unsigned)NBLK)
      __builtin_amdgcn_s_sleep(1);
    __builtin_amdgcn_fence(__ATOMIC_ACQUIRE, "agent");
    ((unsigned*)Wlds)[0] = xcc_;
    ((unsigned*)Wlds)[1] = (idx_ == 0u) ? 1u : 0u;
  }
  __syncthreads();
  const int xcc = (int)((unsigned*)Wlds)[0];
  const int is_leader = (int)((unsigned*)Wlds)[1];
  __syncthreads();

  // one-time: W slice global -> LDS
  {
    const f32x4* src = (const f32x4*)(WT + (size_t)jg * 65536);
    f32x4* dst = (f32x4*)Wlds;
    for (int u = tid; u < 8192; u += NTHR) dst[u] = src[u];
  }
  // h in registers, MFMA C layout
  float h[2][4];
  {
    float a0 = h0[col0], a1 = h0[col0 + 16];
#pragma unroll
    for (int q = 0; q < 4; ++q) { h[0][q] = a0; h[1][q] = a1; }
  }
  float wic[4][2];
#pragma unroll
  for (int i = 0; i < 4; ++i) {
    wic[i][0] = wi_full[i * HDIM + col0];
    wic[i][1] = wi_full[i * HDIM + col0 + 16];
  }
  // wo for register epilogue: this lane's 2 cols, both outputs
  const float wo0a = wo_full[col0], wo0b = wo_full[col0 + 16];
  const float wo1a = wo_full[HDIM + col0], wo1b = wo_full[HDIM + col0 + 16];
  __syncthreads();

  // prefetch t=0 noise + input
  float nz[2][4]; float4 xv[4];
#pragma unroll
  for (int q = 0; q < 4; ++q) {
    const int brow = b0w + hi * 4 + q;
    const float* np = noise + ((size_t)brow * TSTEPS + 0) * HDIM;
    nz[0][q] = np[col0];
    nz[1][q] = np[col0 + 16];
    xv[q] = *(const float4*)(inp + ((size_t)brow * TSTEPS + 0) * 4);
  }

  for (int t = 0; t < TSTEPS; ++t) {
    const unsigned short* rr = rbuf + (size_t)(t & 1) * (BATCH * HDIM);
    unsigned short* rw = rbuf + (size_t)((t + 1) & 1) * (BATCH * HDIM);

    // ---- rec = r_t @ wrec.T, 16-deep register-ring A pipeline (cached loads) ----
    const bf16x8* ap = (const bf16x8*)(rr + (size_t)(b0w + lr) * HDIM + hi * 8);
    bf16x8 ar[16];
#pragma unroll
    for (int i = 0; i < 16; ++i) ar[i] = ap[i * 4];
    f32x4 acc0 = {0.f, 0.f, 0.f, 0.f}, acc1 = {0.f, 0.f, 0.f, 0.f};
    const bf16x8* Ws = (const bf16x8*)Wlds;
#pragma unroll
    for (int kb = 0; kb < 64; ++kb) {
      bf16x8 a = ar[kb & 15];
      bf16x8 bA = Ws[(kb * 2 + 0) * 64 + l];
      bf16x8 bB = Ws[(kb * 2 + 1) * 64 + l];
      acc0 = __builtin_amdgcn_mfma_f32_16x16x32_bf16(a, bA, acc0, 0, 0, 0);
      acc1 = __builtin_amdgcn_mfma_f32_16x16x32_bf16(a, bB, acc1, 0, 0, 0);
      if (kb < 48) ar[kb & 15] = ap[(kb + 16) * 4];
    }

    // ---- h update + write r_{t+1} write-through (no dirty L2 lines) ----
    float ro[2][4];
#pragma unroll
    for (int q = 0; q < 4; ++q) {
      float x0 = xv[q].x * wic[0][0] + xv[q].y * wic[1][0] + xv[q].z * wic[2][0] + xv[q].w * wic[3][0];
      float x1 = xv[q].x * wic[0][1] + xv[q].y * wic[1][1] + xv[q].z * wic[2][1] + xv[q].w * wic[3][1];
      float h0n = 0.8f * h[0][q] + 0.05f * nz[0][q] + 0.2f * (acc0[q] + x0);
      float h1n = 0.8f * h[1][q] + 0.05f * nz[1][q] + 0.2f * (acc1[q] + x1);
      h[0][q] = h0n; h[1][q] = h1n;
      float r0_ = tanh_fast(h0n), r1_ = tanh_fast(h1n);
      ro[0][q] = r0_; ro[1][q] = r1_;
      const int brow = b0w + hi * 4 + q;
      unsigned short* rp = rw + (size_t)brow * HDIM;
      st_bf16_wt(rp + col0, f2bf(r0_));
      st_bf16_wt(rp + col0 + 16, f2bf(r1_));
    }

    // ---- arrive: drain write-through stores (acked at coherence point), flag ----
    asm volatile("s_waitcnt vmcnt(0)" ::: "memory");
    __syncthreads();
    if (t + 1 < TSTEPS && tid == 0)
      __hip_atomic_store(bar + B_FLAGS + bid, (unsigned)(t + 1), __ATOMIC_RELAXED, AGENT);

    // ---- hidden under barrier: out_t from register r (R6-proven epilogue) ----
#pragma unroll
    for (int q = 0; q < 4; ++q) {
      float p0 = ro[0][q] * wo0a + ro[1][q] * wo0b;
      float p1 = ro[0][q] * wo1a + ro[1][q] * wo1b;
      p0 += __shfl_xor(p0, 1, 64); p1 += __shfl_xor(p1, 1, 64);
      p0 += __shfl_xor(p0, 2, 64); p1 += __shfl_xor(p1, 2, 64);
      p0 += __shfl_xor(p0, 4, 64); p1 += __shfl_xor(p1, 4, 64);
      p0 += __shfl_xor(p0, 8, 64); p1 += __shfl_xor(p1, 8, 64);
      if (lr == 0) {
        const int brow = b0w + hi * 4 + q;
        float* op = out + (size_t)brow * (TSTEPS * 2) + (size_t)t * 2;
        atomicAdd(op, p0);
        atomicAdd(op + 1, p1);
      }
    }

    if (t + 1 < TSTEPS) {
      // ---- hidden under barrier: prefetch t+1 noise + input ----
#pragma unroll
      for (int q = 0; q < 4; ++q) {
        const int brow = b0w + hi * 4 + q;
        const float* np = noise + ((size_t)brow * TSTEPS + (t + 1)) * HDIM;
        nz[0][q] = np[col0];
        nz[1][q] = np[col0 + 16];
        xv[q] = *(const float4*)(inp + ((size_t)brow * TSTEPS + (t + 1)) * 4);
      }
      // ---- wait: leader polls all 256 flags (4 coalesced rounds in wave 0),
      //      does the single per-XCD ACQUIRE (L2 inv), posts ready; siblings
      //      poll ready. Then all blocks L1-inv. (All pieces R4/R8-proven.) ----
      if (is_leader) {
        if (w == 0) {
          const unsigned tgt = (unsigned)(t + 1);
          for (;;) {
            unsigned f0 = __hip_atomic_load(bar + B_FLAGS + l, __ATOMIC_RELAXED, AGENT);
            unsigned f1 = __hip_atomic_load(bar + B_FLAGS + 64 + l, __ATOMIC_RELAXED, AGENT);
            unsigned f2 = __hip_atomic_load(bar + B_FLAGS + 128 + l, __ATOMIC_RELAXED, AGENT);
            unsigned f3 = __hip_atomic_load(bar + B_FLAGS + 192 + l, __ATOMIC_RELAXED, AGENT);
            unsigned mn = min(min(f0, f1), min(f2, f3));
            if (__all((int)(mn >= tgt))) break;
          }
          if (l == 0) {
            __builtin_amdgcn_fence(__ATOMIC_ACQUIRE, "agent");  // inv L1+L2 (this XCD)
            __hip_atomic_store(bar + B_RDY(xcc), (unsigned)(t + 1), __ATOMIC_RELAXED, AGENT);
          }
        }
      } else {
        if (tid == 0) {
          while (__hip_atomic_load(bar + B_RDY(xcc), __ATOMIC_RELAXED, AGENT) < (unsigned)(t + 1)) {}
        }
      }
      __syncthreads();
      // per-CU L1 invalidate (L2 already inv'd by this XCD's leader)
      asm volatile("buffer_inv" ::: "memory");
      asm volatile("s_waitcnt vmcnt(0)" ::: "memory");
      __builtin_amdgcn_sched_barrier(0);
    }
  }
}

extern "C" void kernel_launch(void* const* d_in, const int* in_sizes, int n_in,
                              void* d_out, int out_size, void* d_ws, size_t ws_size,
                              hipStream_t stream) {
  const float* inp = (const float*)d_in[0];
  const float* noise = (const float*)d_in[1];
  const float* wi = (const float*)d_in[2];
  const float* si = (const float*)d_in[3];
  const float* m = (const float*)d_in[4];
  const float* n = (const float*)d_in[5];
  const float* rec_noise = (const float*)d_in[6];
  const float* wo = (const float*)d_in[7];
  const float* so = (const float*)d_in[8];
  const float* h0 = (const float*)d_in[9];

  char* ws = (char*)d_ws;
  unsigned short* WT = (unsigned short*)(ws + WT_OFF);
  unsigned short* rbuf = (unsigned short*)(ws + RBUF_OFF);
  float* wi_full = (float*)(ws + WI_OFF);
  float* wo_full = (float*)(ws + WO_OFF);
  unsigned* bar = (unsigned*)(ws + BAR_OFF);
  float* outp = (float*)d_out;

  // rebuild proxy params every call (ws is poisoned before timing)
  prep_wt<<<4096, 256, 0, stream>>>(rec_noise, m, n, WT);
  prep_small<<<2048, 256, 0, stream>>>(wi, si, wo, so, h0, wi_full, wo_full, rbuf);
  hipMemsetAsync(d_out, 0, (size_t)out_size * sizeof(float), stream);
  hipMemsetAsync(bar, 0, 4096, stream);

  hipFuncSetAttribute((const void*)rnn_run, hipFuncAttributeMaxDynamicSharedMemorySize, 131072);
  const unsigned short* WTc = WT;
  void* kargs[9] = {(void*)&inp, (void*)&noise, (void*)&WTc, (void*)&rbuf,
                    (void*)&wi_full, (void*)&wo_full, (void*)&h0, (void*)&outp,
                    (void*)&bar};
  hipError_t lerr = hipLaunchCooperativeKernel((void*)rnn_run, dim3(NBLK), dim3(NTHR),
                                               kargs, 131072, stream);
  if (lerr != hipSuccess) {
    rnn_run<<<dim3(NBLK), dim3(NTHR), 131072, stream>>>(
        inp, noise, WT, rbuf, wi_full, wo_full, h0, outp, bar);
  }
}

// Round 13
// 3953.297 us; speedup vs baseline: 1.7949x; 1.1091x over previous
//
#include <hip/hip_runtime.h>

typedef float f32x4 __attribute__((ext_vector_type(4)));
typedef __bf16 bf16x8 __attribute__((ext_vector_type(8)));

#define HDIM 2048
#define BATCH 256
#define TSTEPS 300
#define NBLK 256
#define NTHR 256

// ws layout (bytes)
#define WT_OFF 0u            // 2048*2048 bf16 = 8388608 B, MFMA B-frag order
#define RBUF_OFF 8388608u    // 2 * 256*2048 bf16 = 2097152 B (double buffer)
#define WI_OFF 10485760u     // 4*2048 f32 = 32768 B
#define WO_OFF 10518528u     // 2*2048 f32 = 16384 B  ([o][j] layout)
#define BAR_OFF 10534912u    // 4 KB barrier area

// bar u32 indices
#define B_FLAGS 0                     // flags[256]: [mg*64 + (xcc&1)*32 + idx]
#define B_RDY(x) (256 + (x) * 32)     // per-XCD ready generation (128B apart)
#define B_GCNT0 520                   // init barrier counter
#define B_XTOT(x) (544 + (x))         // per-XCD registration counters

#define AGENT __HIP_MEMORY_SCOPE_AGENT

__device__ inline float tanh_fast(float x) {
  float e = __expf(2.0f * x);
  return 1.0f - 2.0f / (e + 1.0f);
}

__device__ inline unsigned short f2bf(float f) {
  union { float f; unsigned u; } v; v.f = f;
  unsigned r = v.u + 0x7fffu + ((v.u >> 16) & 1u);
  return (unsigned short)(r >> 16);
}

// write-through (sc0 sc1) 16-bit store (R11/R12-proven release building block)
__device__ inline void st_bf16_wt(unsigned short* p, unsigned short v) {
  unsigned vv = v;
  asm volatile("global_store_short %0, %1, off sc0 sc1" :: "v"(p), "v"(vv) : "memory");
}

// Build wrec^T in bf16, MFMA B-frag order (verified rounds 1-12)
__global__ void prep_wt(const float* __restrict__ rec_noise,
                        const float* __restrict__ m, const float* __restrict__ n,
                        unsigned short* __restrict__ WT) {
  int base = (blockIdx.x * 256 + threadIdx.x) * 4;
#pragma unroll
  for (int ii = 0; ii < 4; ++ii) {
    int e = base + ii;
    int i = e & 7;
    int lane = (e >> 3) & 63;
    int t16 = (e >> 9) & 1;
    int kb = (e >> 10) & 63;
    int jg = e >> 16;
    int j = jg * 32 + t16 * 16 + (lane & 15);
    int k = kb * 32 + (lane >> 4) * 8 + i;
    float v = rec_noise[(size_t)j * HDIM + k] + m[j * 2] * n[k * 2] + m[j * 2 + 1] * n[k * 2 + 1];
    WT[e] = f2bf(v);
  }
}

__global__ void prep_small(const float* __restrict__ wi, const float* __restrict__ si,
                           const float* __restrict__ wo, const float* __restrict__ so,
                           const float* __restrict__ h0,
                           float* __restrict__ wi_full, float* __restrict__ wo_full,
                           unsigned short* __restrict__ r0) {
  int idx = blockIdx.x * 256 + threadIdx.x;
  if (idx < BATCH * HDIM) {
    int j = idx & (HDIM - 1);
    r0[idx] = f2bf(tanh_fast(h0[j]));
  }
  if (idx < 4 * HDIM) wi_full[idx] = wi[idx] * si[idx >> 11];
  if (idx < 2 * HDIM) {
    int o = idx >> 11, j = idx & (HDIM - 1);
    wo_full[idx] = wo[j * 2 + o] * so[o];
  }
}

// R12 structure, decoupled into 4 independent row-group pipelines pinned to XCD
// pairs: mg = xcc>>1 (64 rows), jg = (xcc&1)*32 + idx (32 cols). Barrier scope =
// 64 blocks on 2 XCDs; each XCD's leader polls its group's 64 flags (one
// coalesced lane round), does the single ACQUIRE (L2 inv), posts ready[xcc].
__global__ __launch_bounds__(NTHR, 1) void rnn_run(
    const float* __restrict__ inp, const float* __restrict__ noise,
    const unsigned short* __restrict__ WT, unsigned short* __restrict__ rbuf,
    const float* __restrict__ wi_full, const float* __restrict__ wo_full,
    const float* __restrict__ h0, float* __restrict__ out,
    unsigned* __restrict__ bar) {
  extern __shared__ unsigned short Wlds[];  // 128 KB: this block's W slice

  const int tid = threadIdx.x;
  const int l = tid & 63, w = tid >> 6;
  const int lr = l & 15, hi = l >> 4;

  // ---- registration: XCD id + index-within-XCD (R4/R6/R8-proven) ----
  if (tid == 0) {
    unsigned xcc_ = (unsigned)__builtin_amdgcn_s_getreg((31u << 11) | 20u) & 7u;  // HW_REG_XCC_ID
    unsigned idx_ = __hip_atomic_fetch_add(bar + B_XTOT(xcc_), 1u, __ATOMIC_RELAXED, AGENT);
    __hip_atomic_fetch_add(bar + B_GCNT0, 1u, __ATOMIC_RELEASE, AGENT);
    while (__hip_atomic_load(bar + B_GCNT0, __ATOMIC_RELAXED, AGENT) < (unsigned)NBLK)
      __builtin_amdgcn_s_sleep(1);
    __builtin_amdgcn_fence(__ATOMIC_ACQUIRE, "agent");
    ((unsigned*)Wlds)[0] = xcc_;
    ((unsigned*)Wlds)[1] = idx_ & 31u;
  }
  __syncthreads();
  const int xcc = (int)((unsigned*)Wlds)[0];
  const int bi = (int)((unsigned*)Wlds)[1];
  __syncthreads();

  const int mg = xcc >> 1;                     // row group: 64 rows, on XCDs {2mg, 2mg+1}
  const int jg = (xcc & 1) * 32 + bi;          // col group [0,64): 32 cols
  const int is_leader = (bi == 0);
  const int b0w = mg * 64 + w * 16;
  const int col0 = jg * 32 + lr;

  // one-time: W slice global -> LDS
  {
    const f32x4* src = (const f32x4*)(WT + (size_t)jg * 65536);
    f32x4* dst = (f32x4*)Wlds;
    for (int u = tid; u < 8192; u += NTHR) dst[u] = src[u];
  }
  // h in registers, MFMA C layout
  float h[2][4];
  {
    float a0 = h0[col0], a1 = h0[col0 + 16];
#pragma unroll
    for (int q = 0; q < 4; ++q) { h[0][q] = a0; h[1][q] = a1; }
  }
  float wic[4][2];
#pragma unroll
  for (int i = 0; i < 4; ++i) {
    wic[i][0] = wi_full[i * HDIM + col0];
    wic[i][1] = wi_full[i * HDIM + col0 + 16];
  }
  const float wo0a = wo_full[col0], wo0b = wo_full[col0 + 16];
  const float wo1a = wo_full[HDIM + col0], wo1b = wo_full[HDIM + col0 + 16];
  __syncthreads();

  // prefetch t=0 noise + input
  float nz[2][4]; float4 xv[4];
#pragma unroll
  for (int q = 0; q < 4; ++q) {
    const int brow = b0w + hi * 4 + q;
    const float* np = noise + ((size_t)brow * TSTEPS + 0) * HDIM;
    nz[0][q] = np[col0];
    nz[1][q] = np[col0 + 16];
    xv[q] = *(const float4*)(inp + ((size_t)brow * TSTEPS + 0) * 4);
  }

  unsigned* myflag = bar + B_FLAGS + mg * 64 + (xcc & 1) * 32 + bi;
  const unsigned* pollp = bar + B_FLAGS + mg * 64 + l;   // 64 flags of my group

  for (int t = 0; t < TSTEPS; ++t) {
    const unsigned short* rr = rbuf + (size_t)(t & 1) * (BATCH * HDIM);
    unsigned short* rw = rbuf + (size_t)((t + 1) & 1) * (BATCH * HDIM);

    // ---- rec = r_t @ wrec.T, 16-deep register-ring A pipeline (cached loads) ----
    const bf16x8* ap = (const bf16x8*)(rr + (size_t)(b0w + lr) * HDIM + hi * 8);
    bf16x8 ar[16];
#pragma unroll
    for (int i = 0; i < 16; ++i) ar[i] = ap[i * 4];
    f32x4 acc0 = {0.f, 0.f, 0.f, 0.f}, acc1 = {0.f, 0.f, 0.f, 0.f};
    const bf16x8* Ws = (const bf16x8*)Wlds;
#pragma unroll
    for (int kb = 0; kb < 64; ++kb) {
      bf16x8 a = ar[kb & 15];
      bf16x8 bA = Ws[(kb * 2 + 0) * 64 + l];
      bf16x8 bB = Ws[(kb * 2 + 1) * 64 + l];
      acc0 = __builtin_amdgcn_mfma_f32_16x16x32_bf16(a, bA, acc0, 0, 0, 0);
      acc1 = __builtin_amdgcn_mfma_f32_16x16x32_bf16(a, bB, acc1, 0, 0, 0);
      if (kb < 48) ar[kb & 15] = ap[(kb + 16) * 4];
    }

    // ---- h update + write r_{t+1} write-through (no dirty L2 lines) ----
    float ro[2][4];
#pragma unroll
    for (int q = 0; q < 4; ++q) {
      float x0 = xv[q].x * wic[0][0] + xv[q].y * wic[1][0] + xv[q].z * wic[2][0] + xv[q].w * wic[3][0];
      float x1 = xv[q].x * wic[0][1] + xv[q].y * wic[1][1] + xv[q].z * wic[2][1] + xv[q].w * wic[3][1];
      float h0n = 0.8f * h[0][q] + 0.05f * nz[0][q] + 0.2f * (acc0[q] + x0);
      float h1n = 0.8f * h[1][q] + 0.05f * nz[1][q] + 0.2f * (acc1[q] + x1);
      h[0][q] = h0n; h[1][q] = h1n;
      float r0_ = tanh_fast(h0n), r1_ = tanh_fast(h1n);
      ro[0][q] = r0_; ro[1][q] = r1_;
      const int brow = b0w + hi * 4 + q;
      unsigned short* rp = rw + (size_t)brow * HDIM;
      st_bf16_wt(rp + col0, f2bf(r0_));
      st_bf16_wt(rp + col0 + 16, f2bf(r1_));
    }

    // ---- arrive: drain write-through stores, then per-group flag (R12-proven) ----
    asm volatile("s_waitcnt vmcnt(0)" ::: "memory");
    __syncthreads();
    if (t + 1 < TSTEPS && tid == 0)
      __hip_atomic_store(myflag, (unsigned)(t + 1), __ATOMIC_RELAXED, AGENT);

    // ---- hidden under barrier: out_t from register r ----
#pragma unroll
    for (int q = 0; q < 4; ++q) {
      float p0 = ro[0][q] * wo0a + ro[1][q] * wo0b;
      float p1 = ro[0][q] * wo1a + ro[1][q] * wo1b;
      p0 += __shfl_xor(p0, 1, 64); p1 += __shfl_xor(p1, 1, 64);
      p0 += __shfl_xor(p0, 2, 64); p1 += __shfl_xor(p1, 2, 64);
      p0 += __shfl_xor(p0, 4, 64); p1 += __shfl_xor(p1, 4, 64);
      p0 += __shfl_xor(p0, 8, 64); p1 += __shfl_xor(p1, 8, 64);
      if (lr == 0) {
        const int brow = b0w + hi * 4 + q;
        float* op = out + (size_t)brow * (TSTEPS * 2) + (size_t)t * 2;
        atomicAdd(op, p0);
        atomicAdd(op + 1, p1);
      }
    }

    if (t + 1 < TSTEPS) {
      // ---- hidden under barrier: prefetch t+1 noise + input ----
#pragma unroll
      for (int q = 0; q < 4; ++q) {
        const int brow = b0w + hi * 4 + q;
        const float* np = noise + ((size_t)brow * TSTEPS + (t + 1)) * HDIM;
        nz[0][q] = np[col0];
        nz[1][q] = np[col0 + 16];
        xv[q] = *(const float4*)(inp + ((size_t)brow * TSTEPS + (t + 1)) * 4);
      }
      // ---- wait: each XCD's leader polls its group's 64 flags (1 coalesced
      //      round), ACQUIRE (L2 inv), posts ready[xcc]; siblings poll ready. ----
      if (is_leader) {
        if (w == 0) {
          const unsigned tgt = (unsigned)(t + 1);
          for (;;) {
            unsigned fv = __hip_atomic_load(pollp, __ATOMIC_RELAXED, AGENT);
            if (__all((int)(fv >= tgt))) break;
          }
          if (l == 0) {
            __builtin_amdgcn_fence(__ATOMIC_ACQUIRE, "agent");  // inv L1+L2 (this XCD)
            __hip_atomic_store(bar + B_RDY(xcc), (unsigned)(t + 1), __ATOMIC_RELAXED, AGENT);
          }
        }
      } else {
        if (tid == 0) {
          while (__hip_atomic_load(bar + B_RDY(xcc), __ATOMIC_RELAXED, AGENT) < (unsigned)(t + 1)) {}
        }
      }
      __syncthreads();
      // per-CU L1 invalidate (L2 already inv'd by this XCD's leader)
      asm volatile("buffer_inv" ::: "memory");
      asm volatile("s_waitcnt vmcnt(0)" ::: "memory");
      __builtin_amdgcn_sched_barrier(0);
    }
  }
}

extern "C" void kernel_launch(void* const* d_in, const int* in_sizes, int n_in,
                              void* d_out, int out_size, void* d_ws, size_t ws_size,
                              hipStream_t stream) {
  const float* inp = (const float*)d_in[0];
  const float* noise = (const float*)d_in[1];
  const float* wi = (const float*)d_in[2];
  const float* si = (const float*)d_in[3];
  const float* m = (const float*)d_in[4];
  const float* n = (const float*)d_in[5];
  const float* rec_noise = (const float*)d_in[6];
  const float* wo = (const float*)d_in[7];
  const float* so = (const float*)d_in[8];
  const float* h0 = (const float*)d_in[9];

  char* ws = (char*)d_ws;
  unsigned short* WT = (unsigned short*)(ws + WT_OFF);
  unsigned short* rbuf = (unsigned short*)(ws + RBUF_OFF);
  float* wi_full = (float*)(ws + WI_OFF);
  float* wo_full = (float*)(ws + WO_OFF);
  unsigned* bar = (unsigned*)(ws + BAR_OFF);
  float* outp = (float*)d_out;

  // rebuild proxy params every call (ws is poisoned before timing)
  prep_wt<<<4096, 256, 0, stream>>>(rec_noise, m, n, WT);
  prep_small<<<2048, 256, 0, stream>>>(wi, si, wo, so, h0, wi_full, wo_full, rbuf);
  hipMemsetAsync(d_out, 0, (size_t)out_size * sizeof(float), stream);
  hipMemsetAsync(bar, 0, 4096, stream);

  hipFuncSetAttribute((const void*)rnn_run, hipFuncAttributeMaxDynamicSharedMemorySize, 131072);
  const unsigned short* WTc = WT;
  void* kargs[9] = {(void*)&inp, (void*)&noise, (void*)&WTc, (void*)&rbuf,
                    (void*)&wi_full, (void*)&wo_full, (void*)&h0, (void*)&outp,
                    (void*)&bar};
  hipError_t lerr = hipLaunchCooperativeKernel((void*)rnn_run, dim3(NBLK), dim3(NTHR),
                                               kargs, 131072, stream);
  if (lerr != hipSuccess) {
    rnn_run<<<dim3(NBLK), dim3(NTHR), 131072, stream>>>(
        inp, noise, WT, rbuf, wi_full, wo_full, h0, outp, bar);
  }
}